// Round 7
// baseline (445.950 us; speedup 1.0000x reference)
//
#include <hip/hip_runtime.h>
#include <hip/hip_cooperative_groups.h>
#include <math.h>

namespace cg = cooperative_groups;

#define NTOK 4096
#define CCH  64
#define LOG2E 1.4426950408889634f

typedef __attribute__((ext_vector_type(8)))  short bf16x8;   // 8 bf16 = 4 VGPRs
typedef __attribute__((ext_vector_type(4)))  float f32x4;
typedef __attribute__((ext_vector_type(16))) float f32x16;
typedef __attribute__((ext_vector_type(2)))  unsigned int uint32x2;

__device__ __forceinline__ unsigned short f2bf_rne(float f) {
    unsigned int u = __float_as_uint(f);
    u += 0x7FFFu + ((u >> 16) & 1u);
    return (unsigned short)(u >> 16);
}
__device__ __forceinline__ unsigned short f2bf_trunc(float f) {
    return (unsigned short)(__float_as_uint(f) >> 16);
}
__device__ __forceinline__ float bf2f(unsigned short u) {
    return __uint_as_float(((unsigned int)u) << 16);
}

// ---------------------------------------------------------------------------
// Shared phase bodies (used by both the fused cooperative kernel and the
// 3-kernel fallback). LDS buffers are passed in.
// ---------------------------------------------------------------------------
struct ProjS {
    unsigned short xsb[64 * 68];   // [n][c] bf16 (B^T storage)
    unsigned short wa[80 * 68];    // [m][c] bf16 (A storage)
    unsigned short vtmp[64 * 66];  // [c][sigma(n)] staging for coalesced store
    float bb[80];
};
struct AttnS {
    unsigned short qs[64 * 32];    // [m][d0..31], d>=8 zero
    unsigned short ks[64 * 40];    // [n][d0..31], d>=8 zero
    unsigned short vs[64 * 88];    // [c][n'] pre-permuted
    unsigned short ps[64 * 88];    // [m][n'] bf16 P
};

__device__ __forceinline__ void proj_tile(
    ProjS& s, int vb, int t,
    const float* __restrict__ x,
    const float* __restrict__ wq, const float* __restrict__ bq,
    const float* __restrict__ wk, const float* __restrict__ bk,
    const float* __restrict__ wv, const float* __restrict__ bv,
    unsigned short* __restrict__ qt, unsigned short* __restrict__ kt,
    unsigned short* __restrict__ vbf)
{
    const int b  = vb >> 6;
    const int n0 = (vb & 63) << 6;
    const int lane = t & 63;
    const int w    = t >> 6;
    const int l15  = lane & 15;
    const int g    = lane >> 4;

    {   // stage x tile transposed to bf16: read [c][n] coalesced -> [n][c]
        const int n  = t & 63;
        const int c0 = t >> 6;
        #pragma unroll
        for (int r = 0; r < 16; ++r) {
            const int c = c0 + 4 * r;
            s.xsb[n * 68 + c] = f2bf_rne(x[((size_t)(b * CCH + c)) * NTOK + n0 + n]);
        }
    }
    #pragma unroll
    for (int r = 0; r < 16; ++r) {   // rows 0-63: wv
        const int i = t + 256 * r;
        s.wa[(i >> 6) * 68 + (i & 63)] = f2bf_rne(wv[i]);
    }
    {   // rows 64-71: wq*log2e, rows 72-79: wk
        const int i0 = t, i1 = t + 256;
        s.wa[(64 + (i0 >> 6)) * 68 + (i0 & 63)] = f2bf_rne(wq[i0] * LOG2E);
        s.wa[(64 + (i1 >> 6)) * 68 + (i1 & 63)] = f2bf_rne(wq[i1] * LOG2E);
        s.wa[(72 + (i0 >> 6)) * 68 + (i0 & 63)] = f2bf_rne(wk[i0]);
        s.wa[(72 + (i1 >> 6)) * 68 + (i1 & 63)] = f2bf_rne(wk[i1]);
    }
    if (t < 80) {
        float bias;
        if (t < 64)      bias = bv[t];
        else if (t < 72) bias = bq[t - 64] * LOG2E;
        else             bias = bk[t - 72];
        s.bb[t] = bias;
    }
    __syncthreads();

    // GEMM: wave w -> n-subtile w, 5 m-tiles of 16
    f32x4 acc[5];
    #pragma unroll
    for (int mt = 0; mt < 5; ++mt) acc[mt] = (f32x4){0.f, 0.f, 0.f, 0.f};
    #pragma unroll
    for (int kc = 0; kc < 2; ++kc) {
        const bf16x8 bx = *(const bf16x8*)&s.xsb[(w * 16 + l15) * 68 + kc * 32 + g * 8];
        #pragma unroll
        for (int mt = 0; mt < 5; ++mt) {
            const bf16x8 aw = *(const bf16x8*)&s.wa[(mt * 16 + l15) * 68 + kc * 32 + g * 8];
            acc[mt] = __builtin_amdgcn_mfma_f32_16x16x32_bf16(aw, bx, acc[mt], 0, 0, 0);
        }
    }

    // epilogue: C col n = w*16+l15, row m = mt*16+g*4+r
    const int n = w * 16 + l15;
    #pragma unroll
    for (int mt = 0; mt < 4; ++mt) {
        #pragma unroll
        for (int r = 0; r < 4; ++r) {
            const int c = mt * 16 + g * 4 + r;
            s.vtmp[c * 66 + 4 * l15 + w] = f2bf_rne(acc[mt][r] + s.bb[c]);
        }
    }
    {
        unsigned short vals[4];
        #pragma unroll
        for (int r = 0; r < 4; ++r)
            vals[r] = f2bf_rne(acc[4][r] + s.bb[64 + g * 4 + r]);
        const unsigned int lo = (unsigned int)vals[0] | ((unsigned int)vals[1] << 16);
        const unsigned int hi = (unsigned int)vals[2] | ((unsigned int)vals[3] << 16);
        unsigned short* dst = ((g < 2) ? qt : kt) +
                              ((size_t)(b * NTOK + n0 + n)) * 8 + (g & 1) * 4;
        *(uint32x2*)dst = (uint32x2){lo, hi};
    }
    __syncthreads();

    {   // coalesced permuted V store
        const int c = t >> 2;
        const int q = t & 3;
        unsigned short* dst = vbf + ((size_t)(b * CCH + c)) * NTOK + n0 + q * 16;
        *(bf16x8*)dst       = *(const bf16x8*)&s.vtmp[c * 66 + q * 16];
        *(bf16x8*)(dst + 8) = *(const bf16x8*)&s.vtmp[c * 66 + q * 16 + 8];
    }
}

__device__ __forceinline__ void attn_tile(
    AttnS& s, int vb, int t, int B,
    const unsigned short* __restrict__ qt, const unsigned short* __restrict__ kt,
    const unsigned short* __restrict__ vbf,
    unsigned short* __restrict__ opart, float* __restrict__ lpart)
{
    const int p    = vb / (B * 64);
    const int rest = vb % (B * 64);
    const int b    = rest >> 6;
    const int m0   = (rest & 63) << 6;

    const int lane = t & 63;
    const int w    = t >> 6;
    const int l15  = lane & 15;
    const int g    = lane >> 4;
    const int l31  = lane & 31;
    const int h    = lane >> 5;

    if (t < 64) {
        *(bf16x8*)&s.qs[t * 32] = *(const bf16x8*)&qt[((size_t)(b * NTOK + m0 + t)) * 8];
        bf16x8 z = {};
        *(bf16x8*)&s.qs[t * 32 + 8]  = z;
        *(bf16x8*)&s.qs[t * 32 + 16] = z;
        *(bf16x8*)&s.qs[t * 32 + 24] = z;
        *(bf16x8*)&s.ks[t * 40 + 8]  = z;
        *(bf16x8*)&s.ks[t * 40 + 16] = z;
        *(bf16x8*)&s.ks[t * 40 + 24] = z;
    }
    __syncthreads();

    const bf16x8 a_q = *(const bf16x8*)&s.qs[(w * 16 + l15) * 32 + g * 8];

    f32x16 oacc;
    #pragma unroll
    for (int i = 0; i < 16; ++i) oacc[i] = 0.f;
    float rs0 = 0.f, rs1 = 0.f, rs2 = 0.f, rs3 = 0.f;

    const int crow = ((w >> 1) * 32 + l31) * 88;
    const int mrow = ((w & 1) * 32 + l31) * 88;

    for (int it = p * 32; it < p * 32 + 32; ++it) {
        const int nt0 = it << 6;
        __syncthreads();

        if (t < 64)
            *(bf16x8*)&s.ks[t * 40] =
                *(const bf16x8*)&kt[((size_t)(b * NTOK + nt0 + t)) * 8];
        #pragma unroll
        for (int r = 0; r < 2; ++r) {
            const int i   = t + 256 * r;
            const int c   = i >> 3;
            const int seg = i & 7;
            *(bf16x8*)&s.vs[c * 88 + seg * 8] =
                *(const bf16x8*)&vbf[((size_t)(b * CCH + c)) * NTOK + nt0 + seg * 8];
        }
        __syncthreads();

        f32x4 s0, s1, s2, s3;
        {
            const bf16x8 bk0 = *(const bf16x8*)&s.ks[( 0 + l15) * 40 + g * 8];
            const bf16x8 bk1 = *(const bf16x8*)&s.ks[(16 + l15) * 40 + g * 8];
            const bf16x8 bk2 = *(const bf16x8*)&s.ks[(32 + l15) * 40 + g * 8];
            const bf16x8 bk3 = *(const bf16x8*)&s.ks[(48 + l15) * 40 + g * 8];
            const f32x4 z = {0.f, 0.f, 0.f, 0.f};
            s0 = __builtin_amdgcn_mfma_f32_16x16x32_bf16(a_q, bk0, z, 0, 0, 0);
            s1 = __builtin_amdgcn_mfma_f32_16x16x32_bf16(a_q, bk1, z, 0, 0, 0);
            s2 = __builtin_amdgcn_mfma_f32_16x16x32_bf16(a_q, bk2, z, 0, 0, 0);
            s3 = __builtin_amdgcn_mfma_f32_16x16x32_bf16(a_q, bk3, z, 0, 0, 0);
        }

        #pragma unroll
        for (int r = 0; r < 4; ++r) {
            const float p0 = exp2f(s0[r]);
            const float p1 = exp2f(s1[r]);
            const float p2 = exp2f(s2[r]);
            const float p3 = exp2f(s3[r]);
            const unsigned int lo = (unsigned int)f2bf_trunc(p0) |
                                    ((unsigned int)f2bf_trunc(p1) << 16);
            const unsigned int hi = (unsigned int)f2bf_trunc(p2) |
                                    ((unsigned int)f2bf_trunc(p3) << 16);
            *(uint32x2*)&s.ps[(w * 16 + g * 4 + r) * 88 + 4 * l15] = (uint32x2){lo, hi};
            const float ssum = (p0 + p1) + (p2 + p3);
            if      (r == 0) rs0 += ssum;
            else if (r == 1) rs1 += ssum;
            else if (r == 2) rs2 += ssum;
            else             rs3 += ssum;
        }
        __syncthreads();

        #pragma unroll
        for (int kc = 0; kc < 4; ++kc) {
            const bf16x8 a_v = *(const bf16x8*)&s.vs[crow + kc * 16 + h * 8];
            const bf16x8 b_p = *(const bf16x8*)&s.ps[mrow + kc * 16 + h * 8];
            oacc = __builtin_amdgcn_mfma_f32_32x32x16_bf16(a_v, b_p, oacc, 0, 0, 0);
        }
    }

    #pragma unroll
    for (int xm = 1; xm <= 8; xm <<= 1) {
        rs0 += __shfl_xor(rs0, xm);
        rs1 += __shfl_xor(rs1, xm);
        rs2 += __shfl_xor(rs2, xm);
        rs3 += __shfl_xor(rs3, xm);
    }
    if (l15 == 0) {
        float* lp = lpart + (size_t)(p * B + b) * NTOK + m0 + w * 16 + g * 4;
        lp[0] = rs0; lp[1] = rs1; lp[2] = rs2; lp[3] = rs3;
    }
    {
        const int mloc = (w & 1) * 32 + l31;
        #pragma unroll
        for (int reg = 0; reg < 16; ++reg) {
            const int c = (w >> 1) * 32 + (reg & 3) + 8 * (reg >> 2) + 4 * h;
            opart[((size_t)((p * B + b) * CCH + c)) * NTOK + m0 + mloc] =
                f2bf_rne(oacc[reg]);
        }
    }
}

__device__ __forceinline__ void combine_span(
    int t, int nblocks, int blockid, int B,
    const unsigned short* __restrict__ opart, const float* __restrict__ lpart,
    const float* __restrict__ x, const float* __restrict__ gamma_p,
    float* __restrict__ out)
{
    const float  gm      = gamma_p[0];
    const size_t nf4     = (size_t)B * CCH * NTOK / 4;
    const size_t ostride = (size_t)B * CCH * NTOK;
    for (size_t f = (size_t)blockid * 256 + t; f < nf4; f += (size_t)nblocks * 256) {
        const int m4 = ((int)(f & 1023)) * 4;   // NTOK/4 = 1024 float4 per row
        const int bc = (int)(f >> 10);
        const int bi = bc >> 6;
        const size_t obase = (size_t)bc * NTOK + m4;

        const ushort4 o1 = *(const ushort4*)&opart[obase];
        const ushort4 o2 = *(const ushort4*)&opart[obase + ostride];
        const float4  l1 = *(const float4*)&lpart[(size_t)bi * NTOK + m4];
        const float4  l2 = *(const float4*)&lpart[(size_t)(B + bi) * NTOK + m4];
        const float4  xv = *(const float4*)&x[obase];

        float4 r;
        r.x = (bf2f(o1.x) + bf2f(o2.x)) * gm / (l1.x + l2.x) + xv.x;
        r.y = (bf2f(o1.y) + bf2f(o2.y)) * gm / (l1.y + l2.y) + xv.y;
        r.z = (bf2f(o1.z) + bf2f(o2.z)) * gm / (l1.z + l2.z) + xv.z;
        r.w = (bf2f(o1.w) + bf2f(o2.w)) * gm / (l1.w + l2.w) + xv.w;
        *(float4*)&out[obase] = r;
    }
}

// ---------------------------------------------------------------------------
// Fused cooperative kernel: grid-stride phases so ANY grid size is correct.
// Grid is clamped host-side to the queried co-residency limit.
// ---------------------------------------------------------------------------
__global__ __launch_bounds__(256, 4) void fused_kernel(
    const float* __restrict__ x,
    const float* __restrict__ wq, const float* __restrict__ bq,
    const float* __restrict__ wk, const float* __restrict__ bk,
    const float* __restrict__ wv, const float* __restrict__ bv,
    const float* __restrict__ gamma_p, float* __restrict__ out,
    unsigned short* __restrict__ qt, unsigned short* __restrict__ kt,
    unsigned short* __restrict__ vbf,
    unsigned short* __restrict__ opart, float* __restrict__ lpart, int B)
{
    __shared__ union { ProjS p; AttnS a; } sm;
    cg::grid_group grid = cg::this_grid();
    const int t = threadIdx.x;

    for (int vb = blockIdx.x; vb < B * 64; vb += gridDim.x) {
        __syncthreads();
        proj_tile(sm.p, vb, t, x, wq, bq, wk, bk, wv, bv, qt, kt, vbf);
    }
    __threadfence();
    grid.sync();

    for (int vb = blockIdx.x; vb < 2 * B * 64; vb += gridDim.x)
        attn_tile(sm.a, vb, t, B, qt, kt, vbf, opart, lpart);
    __threadfence();
    grid.sync();

    combine_span(t, gridDim.x, blockIdx.x, B, opart, lpart, x, gamma_p, out);
}

// ---------------------------------------------------------------------------
// Fallback path: round-5's proven three kernels (135.7 us).
// ---------------------------------------------------------------------------
__global__ __launch_bounds__(256) void proj_kernel(
    const float* __restrict__ x,
    const float* __restrict__ wq, const float* __restrict__ bq,
    const float* __restrict__ wk, const float* __restrict__ bk,
    const float* __restrict__ wv, const float* __restrict__ bv,
    unsigned short* __restrict__ qt, unsigned short* __restrict__ kt,
    unsigned short* __restrict__ vbf)
{
    __shared__ ProjS s;
    proj_tile(s, blockIdx.x, threadIdx.x, x, wq, bq, wk, bk, wv, bv, qt, kt, vbf);
}

__global__ __launch_bounds__(256, 4) void attn_kernel(
    const unsigned short* __restrict__ qt, const unsigned short* __restrict__ kt,
    const unsigned short* __restrict__ vbf,
    unsigned short* __restrict__ opart, float* __restrict__ lpart, int B)
{
    __shared__ AttnS s;
    attn_tile(s, blockIdx.x, threadIdx.x, B, qt, kt, vbf, opart, lpart);
}

__global__ __launch_bounds__(256) void combine_kernel(
    const unsigned short* __restrict__ opart, const float* __restrict__ lpart,
    const float* __restrict__ x, const float* __restrict__ gamma_p,
    float* __restrict__ out, int B)
{
    combine_span(threadIdx.x, gridDim.x, blockIdx.x, B, opart, lpart, x, gamma_p, out);
}

extern "C" void kernel_launch(void* const* d_in, const int* in_sizes, int n_in,
                              void* d_out, int out_size, void* d_ws, size_t ws_size,
                              hipStream_t stream) {
    const float* x     = (const float*)d_in[0];
    const float* wq    = (const float*)d_in[1];
    const float* bq    = (const float*)d_in[2];
    const float* wk    = (const float*)d_in[3];
    const float* bk    = (const float*)d_in[4];
    const float* wv    = (const float*)d_in[5];
    const float* bv    = (const float*)d_in[6];
    const float* gamma = (const float*)d_in[7];
    float* out = (float*)d_out;

    int B = in_sizes[0] / (CCH * NTOK);   // 8

    // Workspace: qt | kt (512KB each) | vbf 4MB | opart bf16 8MB | lpart 256KB
    unsigned short* wsp   = (unsigned short*)d_ws;
    unsigned short* qt    = wsp;
    unsigned short* kt    = qt + (size_t)B * NTOK * 8;
    unsigned short* vbf   = kt + (size_t)B * NTOK * 8;
    unsigned short* opart = vbf + (size_t)B * CCH * NTOK;
    float*          lpart = (float*)(opart + (size_t)2 * B * CCH * NTOK);

    // Query real co-residency instead of assuming (round-6 bug: assumed
    // 4 blocks/CU, launch was rejected). Host-side queries are capture-safe.
    int dev = 0;
    (void)hipGetDevice(&dev);
    int numCU = 0;
    (void)hipDeviceGetAttribute(&numCU, hipDeviceAttributeMultiprocessorCount, dev);
    int perCU = 0;
    hipError_t qerr = hipOccupancyMaxActiveBlocksPerMultiprocessor(
        &perCU, (const void*)fused_kernel, 256, 0);

    const int want = 2 * B * 64;   // 1024
    int grid = 0;
    if (qerr == hipSuccess && perCU > 0 && numCU > 0) {
        grid = perCU * numCU;
        if (grid > want) grid = want;
    }

    hipError_t lerr = hipErrorUnknown;
    if (grid >= 64) {
        void* args[] = {
            (void*)&x,  (void*)&wq, (void*)&bq, (void*)&wk, (void*)&bk,
            (void*)&wv, (void*)&bv, (void*)&gamma, (void*)&out,
            (void*)&qt, (void*)&kt, (void*)&vbf, (void*)&opart, (void*)&lpart,
            (void*)&B
        };
        lerr = hipLaunchCooperativeKernel((const void*)fused_kernel, dim3(grid),
                                          dim3(256), args, 0, stream);
    }
    if (lerr != hipSuccess) {
        (void)hipGetLastError();   // clear the error, take the proven path
        proj_kernel<<<B * 64, 256, 0, stream>>>(x, wq, bq, wk, bk, wv, bv,
                                                qt, kt, vbf);
        attn_kernel<<<2 * B * 64, 256, 0, stream>>>(qt, kt, vbf, opart, lpart, B);
        combine_kernel<<<256, 256, 0, stream>>>(opart, lpart, x, gamma, out, B);
    }
}

// Round 8
// 269.039 us; speedup vs baseline: 1.6576x; 1.6576x over previous
//
#include <hip/hip_runtime.h>
#include <math.h>

#define NTOK 4096
#define CCH  64
#define LOG2E 1.4426950408889634f

typedef __attribute__((ext_vector_type(8)))  short bf16x8;   // 8 bf16 = 4 VGPRs
typedef __attribute__((ext_vector_type(4)))  float f32x4;
typedef __attribute__((ext_vector_type(16))) float f32x16;
typedef __attribute__((ext_vector_type(2)))  unsigned int uint32x2;

__device__ __forceinline__ unsigned short f2bf_rne(float f) {
    unsigned int u = __float_as_uint(f);
    u += 0x7FFFu + ((u >> 16) & 1u);
    return (unsigned short)(u >> 16);
}
__device__ __forceinline__ float bf2f(unsigned short u) {
    return __uint_as_float(((unsigned int)u) << 16);
}

// ---------------------------------------------------------------------------
// Kernel 1: MFMA projections (round-5 proven). One GEMM per (b, 64-token
// tile): D[80x64] = [wv ; wq*log2e ; wk] * x_tile. Outputs qt/kt[b][n][8]
// (q pre-scaled by log2e) and vbf[b][c][tile*64 + sigma(nu)],
// sigma(nu) = 4*(nu&15) + (nu>>4)  (matches attn's ps column permutation).
// ---------------------------------------------------------------------------
__global__ __launch_bounds__(256) void proj_kernel(
    const float* __restrict__ x,
    const float* __restrict__ wq, const float* __restrict__ bq,
    const float* __restrict__ wk, const float* __restrict__ bk,
    const float* __restrict__ wv, const float* __restrict__ bv,
    unsigned short* __restrict__ qt, unsigned short* __restrict__ kt,
    unsigned short* __restrict__ vbf)
{
    __shared__ unsigned short xsb[64 * 68];  // [n][c] bf16 (B^T storage)
    __shared__ unsigned short wa[80 * 68];   // [m][c] bf16 (A storage)
    __shared__ unsigned short vtmp[64 * 66]; // [c][sigma(n)]
    __shared__ float bb[80];

    const int t  = threadIdx.x;
    const int b  = blockIdx.x >> 6;
    const int n0 = (blockIdx.x & 63) << 6;

    const int lane = t & 63;
    const int w    = t >> 6;
    const int l15  = lane & 15;
    const int g    = lane >> 4;

    {
        const int n  = t & 63;
        const int c0 = t >> 6;
        #pragma unroll
        for (int r = 0; r < 16; ++r) {
            const int c = c0 + 4 * r;
            xsb[n * 68 + c] = f2bf_rne(x[((size_t)(b * CCH + c)) * NTOK + n0 + n]);
        }
    }
    #pragma unroll
    for (int r = 0; r < 16; ++r) {
        const int i = t + 256 * r;
        wa[(i >> 6) * 68 + (i & 63)] = f2bf_rne(wv[i]);
    }
    {
        const int i0 = t, i1 = t + 256;
        wa[(64 + (i0 >> 6)) * 68 + (i0 & 63)] = f2bf_rne(wq[i0] * LOG2E);
        wa[(64 + (i1 >> 6)) * 68 + (i1 & 63)] = f2bf_rne(wq[i1] * LOG2E);
        wa[(72 + (i0 >> 6)) * 68 + (i0 & 63)] = f2bf_rne(wk[i0]);
        wa[(72 + (i1 >> 6)) * 68 + (i1 & 63)] = f2bf_rne(wk[i1]);
    }
    if (t < 80) {
        float bias;
        if (t < 64)      bias = bv[t];
        else if (t < 72) bias = bq[t - 64] * LOG2E;
        else             bias = bk[t - 72];
        bb[t] = bias;
    }
    __syncthreads();

    f32x4 acc[5];
    #pragma unroll
    for (int mt = 0; mt < 5; ++mt) acc[mt] = (f32x4){0.f, 0.f, 0.f, 0.f};
    #pragma unroll
    for (int kc = 0; kc < 2; ++kc) {
        const bf16x8 bx = *(const bf16x8*)&xsb[(w * 16 + l15) * 68 + kc * 32 + g * 8];
        #pragma unroll
        for (int mt = 0; mt < 5; ++mt) {
            const bf16x8 aw = *(const bf16x8*)&wa[(mt * 16 + l15) * 68 + kc * 32 + g * 8];
            acc[mt] = __builtin_amdgcn_mfma_f32_16x16x32_bf16(aw, bx, acc[mt], 0, 0, 0);
        }
    }

    const int n = w * 16 + l15;
    #pragma unroll
    for (int mt = 0; mt < 4; ++mt) {
        #pragma unroll
        for (int r = 0; r < 4; ++r) {
            const int c = mt * 16 + g * 4 + r;
            vtmp[c * 66 + 4 * l15 + w] = f2bf_rne(acc[mt][r] + bb[c]);
        }
    }
    {
        unsigned short vals[4];
        #pragma unroll
        for (int r = 0; r < 4; ++r)
            vals[r] = f2bf_rne(acc[4][r] + bb[64 + g * 4 + r]);
        const unsigned int lo = (unsigned int)vals[0] | ((unsigned int)vals[1] << 16);
        const unsigned int hi = (unsigned int)vals[2] | ((unsigned int)vals[3] << 16);
        unsigned short* dst = ((g < 2) ? qt : kt) +
                              ((size_t)(b * NTOK + n0 + n)) * 8 + (g & 1) * 4;
        *(uint32x2*)dst = (uint32x2){lo, hi};
    }
    __syncthreads();

    {
        const int c = t >> 2;
        const int q = t & 3;
        unsigned short* dst = vbf + ((size_t)(b * CCH + c)) * NTOK + n0 + q * 16;
        *(bf16x8*)dst       = *(const bf16x8*)&vtmp[c * 66 + q * 16];
        *(bf16x8*)(dst + 8) = *(const bf16x8*)&vtmp[c * 66 + q * 16 + 8];
    }
}

// ---------------------------------------------------------------------------
// Kernel 2: MFMA flash attention, KV-split 2 ways + TICKET-FUSED combine.
// Grid 2*B*64; block = part*512 + b*64 + mtile. Sum-softmax partials are
// exactly additive. After storing (O,L) partials, each block bumps a
// device-scope ticket; the SECOND finisher for a (b,mtile) acquires and
// performs that tile's combine: out = gamma*(O1+O2)/(L1+L2) + x.
// (Replaces the separate combine kernel -> one fewer graph node.)
// ---------------------------------------------------------------------------
__global__ __launch_bounds__(256, 4) void attn_kernel(
    const unsigned short* __restrict__ qt, const unsigned short* __restrict__ kt,
    const unsigned short* __restrict__ vbf,
    unsigned short* __restrict__ opart, float* __restrict__ lpart,
    int* __restrict__ tickets,
    const float* __restrict__ x, const float* __restrict__ gamma_p,
    float* __restrict__ out, int B)
{
    __shared__ unsigned short qs[64 * 32];  // [m][d0..31], d>=8 zero
    __shared__ unsigned short ks[64 * 40];  // [n][d0..31], d>=8 zero
    __shared__ unsigned short vs[64 * 88];  // [c][n'] pre-permuted
    __shared__ unsigned short ps[64 * 88];  // [m][n'] bf16 P
    __shared__ int do_comb;

    const int t    = threadIdx.x;
    const int lane = t & 63;
    const int w    = t >> 6;
    const int p    = blockIdx.x / (B * 64);
    const int rest = blockIdx.x % (B * 64);
    const int b    = rest >> 6;
    const int m0   = (rest & 63) << 6;

    const int l15 = lane & 15;
    const int g   = lane >> 4;
    const int l31 = lane & 31;
    const int h   = lane >> 5;

    if (t < 64) {
        *(bf16x8*)&qs[t * 32] = *(const bf16x8*)&qt[((size_t)(b * NTOK + m0 + t)) * 8];
        bf16x8 z = {};
        *(bf16x8*)&qs[t * 32 + 8]  = z;
        *(bf16x8*)&qs[t * 32 + 16] = z;
        *(bf16x8*)&qs[t * 32 + 24] = z;
        *(bf16x8*)&ks[t * 40 + 8]  = z;
        *(bf16x8*)&ks[t * 40 + 16] = z;
        *(bf16x8*)&ks[t * 40 + 24] = z;
    }
    __syncthreads();

    const bf16x8 a_q = *(const bf16x8*)&qs[(w * 16 + l15) * 32 + g * 8];

    f32x16 oacc;
    #pragma unroll
    for (int i = 0; i < 16; ++i) oacc[i] = 0.f;
    float rs0 = 0.f, rs1 = 0.f, rs2 = 0.f, rs3 = 0.f;

    const int crow = ((w >> 1) * 32 + l31) * 88;
    const int mrow = ((w & 1) * 32 + l31) * 88;

    for (int it = p * 32; it < p * 32 + 32; ++it) {
        const int nt0 = it << 6;
        __syncthreads();

        if (t < 64)
            *(bf16x8*)&ks[t * 40] =
                *(const bf16x8*)&kt[((size_t)(b * NTOK + nt0 + t)) * 8];
        #pragma unroll
        for (int r = 0; r < 2; ++r) {
            const int i   = t + 256 * r;
            const int c   = i >> 3;
            const int seg = i & 7;
            *(bf16x8*)&vs[c * 88 + seg * 8] =
                *(const bf16x8*)&vbf[((size_t)(b * CCH + c)) * NTOK + nt0 + seg * 8];
        }
        __syncthreads();

        f32x4 s0, s1, s2, s3;
        {
            const bf16x8 bk0 = *(const bf16x8*)&ks[( 0 + l15) * 40 + g * 8];
            const bf16x8 bk1 = *(const bf16x8*)&ks[(16 + l15) * 40 + g * 8];
            const bf16x8 bk2 = *(const bf16x8*)&ks[(32 + l15) * 40 + g * 8];
            const bf16x8 bk3 = *(const bf16x8*)&ks[(48 + l15) * 40 + g * 8];
            const f32x4 z = {0.f, 0.f, 0.f, 0.f};
            s0 = __builtin_amdgcn_mfma_f32_16x16x32_bf16(a_q, bk0, z, 0, 0, 0);
            s1 = __builtin_amdgcn_mfma_f32_16x16x32_bf16(a_q, bk1, z, 0, 0, 0);
            s2 = __builtin_amdgcn_mfma_f32_16x16x32_bf16(a_q, bk2, z, 0, 0, 0);
            s3 = __builtin_amdgcn_mfma_f32_16x16x32_bf16(a_q, bk3, z, 0, 0, 0);
        }

        #pragma unroll
        for (int r = 0; r < 4; ++r) {
            const float p0 = exp2f(s0[r]);
            const float p1 = exp2f(s1[r]);
            const float p2 = exp2f(s2[r]);
            const float p3 = exp2f(s3[r]);
            // v_perm_b32 packs the two bf16 truncations in ONE instruction:
            // bytes {p1[3],p1[2],p0[3],p0[2]}
            const unsigned int lo = __builtin_amdgcn_perm(
                __float_as_uint(p1), __float_as_uint(p0), 0x07060302u);
            const unsigned int hi = __builtin_amdgcn_perm(
                __float_as_uint(p3), __float_as_uint(p2), 0x07060302u);
            *(uint32x2*)&ps[(w * 16 + g * 4 + r) * 88 + 4 * l15] = (uint32x2){lo, hi};
            const float ssum = (p0 + p1) + (p2 + p3);
            if      (r == 0) rs0 += ssum;
            else if (r == 1) rs1 += ssum;
            else if (r == 2) rs2 += ssum;
            else             rs3 += ssum;
        }
        __syncthreads();

        #pragma unroll
        for (int kc = 0; kc < 4; ++kc) {
            const bf16x8 a_v = *(const bf16x8*)&vs[crow + kc * 16 + h * 8];
            const bf16x8 b_p = *(const bf16x8*)&ps[mrow + kc * 16 + h * 8];
            oacc = __builtin_amdgcn_mfma_f32_32x32x16_bf16(a_v, b_p, oacc, 0, 0, 0);
        }
    }

    #pragma unroll
    for (int xm = 1; xm <= 8; xm <<= 1) {
        rs0 += __shfl_xor(rs0, xm);
        rs1 += __shfl_xor(rs1, xm);
        rs2 += __shfl_xor(rs2, xm);
        rs3 += __shfl_xor(rs3, xm);
    }
    if (l15 == 0) {
        float* lp = lpart + (size_t)(p * B + b) * NTOK + m0 + w * 16 + g * 4;
        lp[0] = rs0; lp[1] = rs1; lp[2] = rs2; lp[3] = rs3;
    }
    {
        const int mloc = (w & 1) * 32 + l31;
        #pragma unroll
        for (int reg = 0; reg < 16; ++reg) {
            const int c = (w >> 1) * 32 + (reg & 3) + 8 * (reg >> 2) + 4 * h;
            opart[((size_t)((p * B + b) * CCH + c)) * NTOK + m0 + mloc] =
                f2bf_rne(oacc[reg]);
        }
    }

    // ---- ticket: second finisher for (b,mtile) combines that tile ----
    __threadfence();          // release our opart/lpart stores (device scope)
    __syncthreads();          // all threads of this block have fenced
    if (t == 0)
        do_comb = (atomicAdd(&tickets[rest], 1) == 1);
    __syncthreads();
    if (do_comb) {
        __threadfence();      // acquire the other part's stores
        const float  gm      = gamma_p[0];
        const size_t ostride = (size_t)B * CCH * NTOK;
        const int c   = t >> 2;
        const int ms0 = (t & 3) * 16;
        const size_t base = (size_t)(b * CCH + c) * NTOK + m0 + ms0;
        #pragma unroll
        for (int j = 0; j < 4; ++j) {
            const size_t obase = base + j * 4;
            const int    mm    = ms0 + j * 4;
            const ushort4 o1 = *(const ushort4*)&opart[obase];
            const ushort4 o2 = *(const ushort4*)&opart[obase + ostride];
            const float4  l1 = *(const float4*)&lpart[(size_t)b * NTOK + m0 + mm];
            const float4  l2 = *(const float4*)&lpart[(size_t)(B + b) * NTOK + m0 + mm];
            const float4  xv = *(const float4*)&x[obase];
            float4 r;
            r.x = (bf2f(o1.x) + bf2f(o2.x)) * gm / (l1.x + l2.x) + xv.x;
            r.y = (bf2f(o1.y) + bf2f(o2.y)) * gm / (l1.y + l2.y) + xv.y;
            r.z = (bf2f(o1.z) + bf2f(o2.z)) * gm / (l1.z + l2.z) + xv.z;
            r.w = (bf2f(o1.w) + bf2f(o2.w)) * gm / (l1.w + l2.w) + xv.w;
            *(float4*)&out[obase] = r;
        }
    }
}

extern "C" void kernel_launch(void* const* d_in, const int* in_sizes, int n_in,
                              void* d_out, int out_size, void* d_ws, size_t ws_size,
                              hipStream_t stream) {
    const float* x     = (const float*)d_in[0];
    const float* wq    = (const float*)d_in[1];
    const float* bq    = (const float*)d_in[2];
    const float* wk    = (const float*)d_in[3];
    const float* bk    = (const float*)d_in[4];
    const float* wv    = (const float*)d_in[5];
    const float* bv    = (const float*)d_in[6];
    const float* gamma = (const float*)d_in[7];
    float* out = (float*)d_out;

    int B = in_sizes[0] / (CCH * NTOK);   // 8

    // Workspace: qt | kt (512KB each) | vbf 4MB | opart bf16 8MB | lpart 256KB
    // | tickets 2KB
    unsigned short* wsp     = (unsigned short*)d_ws;
    unsigned short* qt      = wsp;
    unsigned short* kt      = qt + (size_t)B * NTOK * 8;
    unsigned short* vbf     = kt + (size_t)B * NTOK * 8;
    unsigned short* opart   = vbf + (size_t)B * CCH * NTOK;
    float*          lpart   = (float*)(opart + (size_t)2 * B * CCH * NTOK);
    int*            tickets = (int*)(lpart + (size_t)2 * B * NTOK);

    // Harness poisons d_ws to 0xAA before every launch -> zero tickets here
    // (hipMemsetAsync is graph-capture legal).
    hipMemsetAsync(tickets, 0, (size_t)B * 64 * sizeof(int), stream);

    proj_kernel<<<B * 64, 256, 0, stream>>>(x, wq, bq, wk, bk, wv, bv, qt, kt, vbf);
    attn_kernel<<<2 * B * 64, 256, 0, stream>>>(qt, kt, vbf, opart, lpart,
                                                tickets, x, gamma, out, B);
}

// Round 9
// 134.512 us; speedup vs baseline: 3.3153x; 2.0001x over previous
//
#include <hip/hip_runtime.h>
#include <math.h>

#define NTOK 4096
#define CCH  64
#define LOG2E 1.4426950408889634f
#define NSPLIT 4   // KV-split ways

typedef __attribute__((ext_vector_type(8)))  short bf16x8;   // 8 bf16 = 4 VGPRs
typedef __attribute__((ext_vector_type(4)))  float f32x4;
typedef __attribute__((ext_vector_type(16))) float f32x16;
typedef __attribute__((ext_vector_type(2)))  unsigned int uint32x2;

__device__ __forceinline__ unsigned short f2bf_rne(float f) {
    unsigned int u = __float_as_uint(f);
    u += 0x7FFFu + ((u >> 16) & 1u);
    return (unsigned short)(u >> 16);
}
__device__ __forceinline__ float bf2f(unsigned short u) {
    return __uint_as_float(((unsigned int)u) << 16);
}

// ---------------------------------------------------------------------------
// Kernel 1: MFMA projections (round-5 proven, unchanged). One GEMM per
// (b, 64-token tile): D[80x64] = [wv ; wq*log2e ; wk] * x_tile.
// Outputs qt/kt[b][n][8] (q pre-scaled by log2e) and
// vbf[b][c][tile*64 + sigma(nu)], sigma(nu) = 4*(nu&15) + (nu>>4).
// ---------------------------------------------------------------------------
__global__ __launch_bounds__(256) void proj_kernel(
    const float* __restrict__ x,
    const float* __restrict__ wq, const float* __restrict__ bq,
    const float* __restrict__ wk, const float* __restrict__ bk,
    const float* __restrict__ wv, const float* __restrict__ bv,
    unsigned short* __restrict__ qt, unsigned short* __restrict__ kt,
    unsigned short* __restrict__ vbf)
{
    __shared__ unsigned short xsb[64 * 68];  // [n][c] bf16 (B^T storage)
    __shared__ unsigned short wa[80 * 68];   // [m][c] bf16 (A storage)
    __shared__ unsigned short vtmp[64 * 66]; // [c][sigma(n)]
    __shared__ float bb[80];

    const int t  = threadIdx.x;
    const int b  = blockIdx.x >> 6;
    const int n0 = (blockIdx.x & 63) << 6;

    const int lane = t & 63;
    const int w    = t >> 6;
    const int l15  = lane & 15;
    const int g    = lane >> 4;

    {
        const int n  = t & 63;
        const int c0 = t >> 6;
        #pragma unroll
        for (int r = 0; r < 16; ++r) {
            const int c = c0 + 4 * r;
            xsb[n * 68 + c] = f2bf_rne(x[((size_t)(b * CCH + c)) * NTOK + n0 + n]);
        }
    }
    #pragma unroll
    for (int r = 0; r < 16; ++r) {
        const int i = t + 256 * r;
        wa[(i >> 6) * 68 + (i & 63)] = f2bf_rne(wv[i]);
    }
    {
        const int i0 = t, i1 = t + 256;
        wa[(64 + (i0 >> 6)) * 68 + (i0 & 63)] = f2bf_rne(wq[i0] * LOG2E);
        wa[(64 + (i1 >> 6)) * 68 + (i1 & 63)] = f2bf_rne(wq[i1] * LOG2E);
        wa[(72 + (i0 >> 6)) * 68 + (i0 & 63)] = f2bf_rne(wk[i0]);
        wa[(72 + (i1 >> 6)) * 68 + (i1 & 63)] = f2bf_rne(wk[i1]);
    }
    if (t < 80) {
        float bias;
        if (t < 64)      bias = bv[t];
        else if (t < 72) bias = bq[t - 64] * LOG2E;
        else             bias = bk[t - 72];
        bb[t] = bias;
    }
    __syncthreads();

    f32x4 acc[5];
    #pragma unroll
    for (int mt = 0; mt < 5; ++mt) acc[mt] = (f32x4){0.f, 0.f, 0.f, 0.f};
    #pragma unroll
    for (int kc = 0; kc < 2; ++kc) {
        const bf16x8 bx = *(const bf16x8*)&xsb[(w * 16 + l15) * 68 + kc * 32 + g * 8];
        #pragma unroll
        for (int mt = 0; mt < 5; ++mt) {
            const bf16x8 aw = *(const bf16x8*)&wa[(mt * 16 + l15) * 68 + kc * 32 + g * 8];
            acc[mt] = __builtin_amdgcn_mfma_f32_16x16x32_bf16(aw, bx, acc[mt], 0, 0, 0);
        }
    }

    const int n = w * 16 + l15;
    #pragma unroll
    for (int mt = 0; mt < 4; ++mt) {
        #pragma unroll
        for (int r = 0; r < 4; ++r) {
            const int c = mt * 16 + g * 4 + r;
            vtmp[c * 66 + 4 * l15 + w] = f2bf_rne(acc[mt][r] + bb[c]);
        }
    }
    {
        unsigned short vals[4];
        #pragma unroll
        for (int r = 0; r < 4; ++r)
            vals[r] = f2bf_rne(acc[4][r] + bb[64 + g * 4 + r]);
        const unsigned int lo = (unsigned int)vals[0] | ((unsigned int)vals[1] << 16);
        const unsigned int hi = (unsigned int)vals[2] | ((unsigned int)vals[3] << 16);
        unsigned short* dst = ((g < 2) ? qt : kt) +
                              ((size_t)(b * NTOK + n0 + n)) * 8 + (g & 1) * 4;
        *(uint32x2*)dst = (uint32x2){lo, hi};
    }
    __syncthreads();

    {
        const int c = t >> 2;
        const int q = t & 3;
        unsigned short* dst = vbf + ((size_t)(b * CCH + c)) * NTOK + n0 + q * 16;
        *(bf16x8*)dst       = *(const bf16x8*)&vtmp[c * 66 + q * 16];
        *(bf16x8*)(dst + 8) = *(const bf16x8*)&vtmp[c * 66 + q * 16 + 8];
    }
}

// ---------------------------------------------------------------------------
// Kernel 2: MFMA flash attention, KV-split 4 ways (sum-softmax partials are
// exactly additive; no rescale, no fences — round-8's ticket/fence fusion
// poisoned L2 and regressed 3.3x, reverted). Grid 4*B*64; block =
// part*512 + b*64 + mtile; part p handles KV tiles [16p, 16p+16).
// ---------------------------------------------------------------------------
__global__ __launch_bounds__(256, 4) void attn_kernel(
    const unsigned short* __restrict__ qt, const unsigned short* __restrict__ kt,
    const unsigned short* __restrict__ vbf,
    unsigned short* __restrict__ opart, float* __restrict__ lpart, int B)
{
    __shared__ unsigned short qs[64 * 32];  // [m][d0..31], d>=8 zero
    __shared__ unsigned short ks[64 * 40];  // [n][d0..31], d>=8 zero
    __shared__ unsigned short vs[64 * 88];  // [c][n'] pre-permuted
    __shared__ unsigned short ps[64 * 88];  // [m][n'] bf16 P

    const int t    = threadIdx.x;
    const int lane = t & 63;
    const int w    = t >> 6;
    const int p    = blockIdx.x / (B * 64);
    const int rest = blockIdx.x % (B * 64);
    const int b    = rest >> 6;
    const int m0   = (rest & 63) << 6;

    const int l15 = lane & 15;
    const int g   = lane >> 4;
    const int l31 = lane & 31;
    const int h   = lane >> 5;

    if (t < 64) {
        *(bf16x8*)&qs[t * 32] = *(const bf16x8*)&qt[((size_t)(b * NTOK + m0 + t)) * 8];
        bf16x8 z = {};
        *(bf16x8*)&qs[t * 32 + 8]  = z;
        *(bf16x8*)&qs[t * 32 + 16] = z;
        *(bf16x8*)&qs[t * 32 + 24] = z;
        *(bf16x8*)&ks[t * 40 + 8]  = z;
        *(bf16x8*)&ks[t * 40 + 16] = z;
        *(bf16x8*)&ks[t * 40 + 24] = z;
    }
    __syncthreads();

    const bf16x8 a_q = *(const bf16x8*)&qs[(w * 16 + l15) * 32 + g * 8];

    f32x16 oacc;
    #pragma unroll
    for (int i = 0; i < 16; ++i) oacc[i] = 0.f;
    float rs0 = 0.f, rs1 = 0.f, rs2 = 0.f, rs3 = 0.f;

    const int crow = ((w >> 1) * 32 + l31) * 88;
    const int mrow = ((w & 1) * 32 + l31) * 88;

    const int itEnd = p * (64 / NSPLIT) + (64 / NSPLIT);
    for (int it = p * (64 / NSPLIT); it < itEnd; ++it) {
        const int nt0 = it << 6;
        __syncthreads();

        if (t < 64)
            *(bf16x8*)&ks[t * 40] =
                *(const bf16x8*)&kt[((size_t)(b * NTOK + nt0 + t)) * 8];
        #pragma unroll
        for (int r = 0; r < 2; ++r) {
            const int i   = t + 256 * r;
            const int c   = i >> 3;
            const int seg = i & 7;
            *(bf16x8*)&vs[c * 88 + seg * 8] =
                *(const bf16x8*)&vbf[((size_t)(b * CCH + c)) * NTOK + nt0 + seg * 8];
        }
        __syncthreads();

        f32x4 s0, s1, s2, s3;
        {
            const bf16x8 bk0 = *(const bf16x8*)&ks[( 0 + l15) * 40 + g * 8];
            const bf16x8 bk1 = *(const bf16x8*)&ks[(16 + l15) * 40 + g * 8];
            const bf16x8 bk2 = *(const bf16x8*)&ks[(32 + l15) * 40 + g * 8];
            const bf16x8 bk3 = *(const bf16x8*)&ks[(48 + l15) * 40 + g * 8];
            const f32x4 z = {0.f, 0.f, 0.f, 0.f};
            s0 = __builtin_amdgcn_mfma_f32_16x16x32_bf16(a_q, bk0, z, 0, 0, 0);
            s1 = __builtin_amdgcn_mfma_f32_16x16x32_bf16(a_q, bk1, z, 0, 0, 0);
            s2 = __builtin_amdgcn_mfma_f32_16x16x32_bf16(a_q, bk2, z, 0, 0, 0);
            s3 = __builtin_amdgcn_mfma_f32_16x16x32_bf16(a_q, bk3, z, 0, 0, 0);
        }

        #pragma unroll
        for (int r = 0; r < 4; ++r) {
            const float p0 = exp2f(s0[r]);
            const float p1 = exp2f(s1[r]);
            const float p2 = exp2f(s2[r]);
            const float p3 = exp2f(s3[r]);
            // v_perm_b32: pack two bf16 truncations in ONE instruction
            const unsigned int lo = __builtin_amdgcn_perm(
                __float_as_uint(p1), __float_as_uint(p0), 0x07060302u);
            const unsigned int hi = __builtin_amdgcn_perm(
                __float_as_uint(p3), __float_as_uint(p2), 0x07060302u);
            *(uint32x2*)&ps[(w * 16 + g * 4 + r) * 88 + 4 * l15] = (uint32x2){lo, hi};
            const float ssum = (p0 + p1) + (p2 + p3);
            if      (r == 0) rs0 += ssum;
            else if (r == 1) rs1 += ssum;
            else if (r == 2) rs2 += ssum;
            else             rs3 += ssum;
        }
        __syncthreads();

        #pragma unroll
        for (int kc = 0; kc < 4; ++kc) {
            const bf16x8 a_v = *(const bf16x8*)&vs[crow + kc * 16 + h * 8];
            const bf16x8 b_p = *(const bf16x8*)&ps[mrow + kc * 16 + h * 8];
            oacc = __builtin_amdgcn_mfma_f32_32x32x16_bf16(a_v, b_p, oacc, 0, 0, 0);
        }
    }

    #pragma unroll
    for (int xm = 1; xm <= 8; xm <<= 1) {
        rs0 += __shfl_xor(rs0, xm);
        rs1 += __shfl_xor(rs1, xm);
        rs2 += __shfl_xor(rs2, xm);
        rs3 += __shfl_xor(rs3, xm);
    }
    if (l15 == 0) {
        float* lp = lpart + (size_t)(p * B + b) * NTOK + m0 + w * 16 + g * 4;
        lp[0] = rs0; lp[1] = rs1; lp[2] = rs2; lp[3] = rs3;
    }
    {
        const int mloc = (w & 1) * 32 + l31;
        #pragma unroll
        for (int reg = 0; reg < 16; ++reg) {
            const int c = (w >> 1) * 32 + (reg & 3) + 8 * (reg >> 2) + 4 * h;
            opart[((size_t)((p * B + b) * CCH + c)) * NTOK + m0 + mloc] =
                f2bf_rne(oacc[reg]);
        }
    }
}

// ---------------------------------------------------------------------------
// Kernel 3: combine NSPLIT partials + normalize + residual (pure streaming).
//   out = gamma * (sum_p O_p) / (sum_p L_p) + x
// ---------------------------------------------------------------------------
__global__ __launch_bounds__(256) void combine_kernel(
    const unsigned short* __restrict__ opart, const float* __restrict__ lpart,
    const float* __restrict__ x, const float* __restrict__ gamma_p,
    float* __restrict__ out, int B)
{
    const float  gm      = gamma_p[0];
    const size_t nf4     = (size_t)B * CCH * NTOK / 4;
    const size_t ostride = (size_t)B * CCH * NTOK;
    for (size_t f = (size_t)blockIdx.x * 256 + threadIdx.x; f < nf4;
         f += (size_t)gridDim.x * 256) {
        const int m4 = ((int)(f & 1023)) * 4;   // NTOK/4 = 1024 float4 per row
        const int bc = (int)(f >> 10);
        const int bi = bc >> 6;
        const size_t obase = (size_t)bc * NTOK + m4;

        float4 osum = {0.f, 0.f, 0.f, 0.f};
        float4 lsum = {0.f, 0.f, 0.f, 0.f};
        #pragma unroll
        for (int p = 0; p < NSPLIT; ++p) {
            const ushort4 o = *(const ushort4*)&opart[obase + (size_t)p * ostride];
            const float4  l = *(const float4*)&lpart[(size_t)(p * B + bi) * NTOK + m4];
            osum.x += bf2f(o.x); osum.y += bf2f(o.y);
            osum.z += bf2f(o.z); osum.w += bf2f(o.w);
            lsum.x += l.x; lsum.y += l.y; lsum.z += l.z; lsum.w += l.w;
        }
        const float4 xv = *(const float4*)&x[obase];
        float4 r;
        r.x = osum.x * gm / lsum.x + xv.x;
        r.y = osum.y * gm / lsum.y + xv.y;
        r.z = osum.z * gm / lsum.z + xv.z;
        r.w = osum.w * gm / lsum.w + xv.w;
        *(float4*)&out[obase] = r;
    }
}

extern "C" void kernel_launch(void* const* d_in, const int* in_sizes, int n_in,
                              void* d_out, int out_size, void* d_ws, size_t ws_size,
                              hipStream_t stream) {
    const float* x     = (const float*)d_in[0];
    const float* wq    = (const float*)d_in[1];
    const float* bq    = (const float*)d_in[2];
    const float* wk    = (const float*)d_in[3];
    const float* bk    = (const float*)d_in[4];
    const float* wv    = (const float*)d_in[5];
    const float* bv    = (const float*)d_in[6];
    const float* gamma = (const float*)d_in[7];
    float* out = (float*)d_out;

    int B = in_sizes[0] / (CCH * NTOK);   // 8

    // Workspace: qt | kt (512KB each) | vbf 4MB | opart bf16 16MB | lpart 512KB
    unsigned short* wsp   = (unsigned short*)d_ws;
    unsigned short* qt    = wsp;
    unsigned short* kt    = qt + (size_t)B * NTOK * 8;
    unsigned short* vbf   = kt + (size_t)B * NTOK * 8;
    unsigned short* opart = vbf + (size_t)B * CCH * NTOK;
    float*          lpart = (float*)(opart + (size_t)NSPLIT * B * CCH * NTOK);

    proj_kernel<<<B * 64, 256, 0, stream>>>(x, wq, bq, wk, bk, wv, bv, qt, kt, vbf);
    attn_kernel<<<NSPLIT * B * 64, 256, 0, stream>>>(qt, kt, vbf, opart, lpart, B);
    combine_kernel<<<512, 256, 0, stream>>>(opart, lpart, x, gamma, out, B);
}

// Round 10
// 134.230 us; speedup vs baseline: 3.3223x; 1.0021x over previous
//
#include <hip/hip_runtime.h>
#include <math.h>

#define NTOK 4096
#define CCH  64
#define LOG2E 1.4426950408889634f
#define NSPLIT 4   // KV-split ways

typedef __attribute__((ext_vector_type(8)))  short bf16x8;   // 8 bf16 = 4 VGPRs
typedef __attribute__((ext_vector_type(4)))  float f32x4;
typedef __attribute__((ext_vector_type(16))) float f32x16;
typedef __attribute__((ext_vector_type(2)))  unsigned int uint32x2;

__device__ __forceinline__ unsigned short f2bf_rne(float f) {
    unsigned int u = __float_as_uint(f);
    u += 0x7FFFu + ((u >> 16) & 1u);
    return (unsigned short)(u >> 16);
}
__device__ __forceinline__ float bf2f(unsigned short u) {
    return __uint_as_float(((unsigned int)u) << 16);
}

// ---------------------------------------------------------------------------
// Kernel 1: MFMA projections (round-5 proven, unchanged). One GEMM per
// (b, 64-token tile): D[80x64] = [wv ; wq*log2e ; wk] * x_tile.
// Outputs qt/kt[b][n][8] (q pre-scaled by log2e) and
// vbf[b][c][tile*64 + sigma(nu)], sigma(nu) = 4*(nu&15) + (nu>>4).
// ---------------------------------------------------------------------------
__global__ __launch_bounds__(256) void proj_kernel(
    const float* __restrict__ x,
    const float* __restrict__ wq, const float* __restrict__ bq,
    const float* __restrict__ wk, const float* __restrict__ bk,
    const float* __restrict__ wv, const float* __restrict__ bv,
    unsigned short* __restrict__ qt, unsigned short* __restrict__ kt,
    unsigned short* __restrict__ vbf)
{
    __shared__ unsigned short xsb[64 * 68];  // [n][c] bf16 (B^T storage)
    __shared__ unsigned short wa[80 * 68];   // [m][c] bf16 (A storage)
    __shared__ unsigned short vtmp[64 * 66]; // [c][sigma(n)]
    __shared__ float bb[80];

    const int t  = threadIdx.x;
    const int b  = blockIdx.x >> 6;
    const int n0 = (blockIdx.x & 63) << 6;

    const int lane = t & 63;
    const int w    = t >> 6;
    const int l15  = lane & 15;
    const int g    = lane >> 4;

    {
        const int n  = t & 63;
        const int c0 = t >> 6;
        #pragma unroll
        for (int r = 0; r < 16; ++r) {
            const int c = c0 + 4 * r;
            xsb[n * 68 + c] = f2bf_rne(x[((size_t)(b * CCH + c)) * NTOK + n0 + n]);
        }
    }
    #pragma unroll
    for (int r = 0; r < 16; ++r) {
        const int i = t + 256 * r;
        wa[(i >> 6) * 68 + (i & 63)] = f2bf_rne(wv[i]);
    }
    {
        const int i0 = t, i1 = t + 256;
        wa[(64 + (i0 >> 6)) * 68 + (i0 & 63)] = f2bf_rne(wq[i0] * LOG2E);
        wa[(64 + (i1 >> 6)) * 68 + (i1 & 63)] = f2bf_rne(wq[i1] * LOG2E);
        wa[(72 + (i0 >> 6)) * 68 + (i0 & 63)] = f2bf_rne(wk[i0]);
        wa[(72 + (i1 >> 6)) * 68 + (i1 & 63)] = f2bf_rne(wk[i1]);
    }
    if (t < 80) {
        float bias;
        if (t < 64)      bias = bv[t];
        else if (t < 72) bias = bq[t - 64] * LOG2E;
        else             bias = bk[t - 72];
        bb[t] = bias;
    }
    __syncthreads();

    f32x4 acc[5];
    #pragma unroll
    for (int mt = 0; mt < 5; ++mt) acc[mt] = (f32x4){0.f, 0.f, 0.f, 0.f};
    #pragma unroll
    for (int kc = 0; kc < 2; ++kc) {
        const bf16x8 bx = *(const bf16x8*)&xsb[(w * 16 + l15) * 68 + kc * 32 + g * 8];
        #pragma unroll
        for (int mt = 0; mt < 5; ++mt) {
            const bf16x8 aw = *(const bf16x8*)&wa[(mt * 16 + l15) * 68 + kc * 32 + g * 8];
            acc[mt] = __builtin_amdgcn_mfma_f32_16x16x32_bf16(aw, bx, acc[mt], 0, 0, 0);
        }
    }

    const int n = w * 16 + l15;
    #pragma unroll
    for (int mt = 0; mt < 4; ++mt) {
        #pragma unroll
        for (int r = 0; r < 4; ++r) {
            const int c = mt * 16 + g * 4 + r;
            vtmp[c * 66 + 4 * l15 + w] = f2bf_rne(acc[mt][r] + bb[c]);
        }
    }
    {
        unsigned short vals[4];
        #pragma unroll
        for (int r = 0; r < 4; ++r)
            vals[r] = f2bf_rne(acc[4][r] + bb[64 + g * 4 + r]);
        const unsigned int lo = (unsigned int)vals[0] | ((unsigned int)vals[1] << 16);
        const unsigned int hi = (unsigned int)vals[2] | ((unsigned int)vals[3] << 16);
        unsigned short* dst = ((g < 2) ? qt : kt) +
                              ((size_t)(b * NTOK + n0 + n)) * 8 + (g & 1) * 4;
        *(uint32x2*)dst = (uint32x2){lo, hi};
    }
    __syncthreads();

    {
        const int c = t >> 2;
        const int q = t & 3;
        unsigned short* dst = vbf + ((size_t)(b * CCH + c)) * NTOK + n0 + q * 16;
        *(bf16x8*)dst       = *(const bf16x8*)&vtmp[c * 66 + q * 16];
        *(bf16x8*)(dst + 8) = *(const bf16x8*)&vtmp[c * 66 + q * 16 + 8];
    }
}

// ---------------------------------------------------------------------------
// Kernel 2: MFMA flash attention, KV-split 4 ways. CHANGES vs round 9:
// Q/K MFMA fragments are loaded DIRECTLY from global (one 16B row per lane,
// only group g==0 nonzero — quarter-wave coalesced, L2-hot, reused by 64
// blocks). qs/ks LDS buffers, their staging, and ONE of the three barriers
// are gone: LDS 31.7->22.5 KB (5 blocks/CU even at 128KB usable),
// 2 syncthreads/iter.
// ---------------------------------------------------------------------------
__global__ __launch_bounds__(256, 6) void attn_kernel(
    const unsigned short* __restrict__ qt, const unsigned short* __restrict__ kt,
    const unsigned short* __restrict__ vbf,
    unsigned short* __restrict__ opart, float* __restrict__ lpart, int B)
{
    __shared__ unsigned short vs[64 * 88];  // [c][n'] pre-permuted
    __shared__ unsigned short ps[64 * 88];  // [m][n'] bf16 P

    const int t    = threadIdx.x;
    const int lane = t & 63;
    const int w    = t >> 6;
    const int p    = blockIdx.x / (B * 64);
    const int rest = blockIdx.x % (B * 64);
    const int b    = rest >> 6;
    const int m0   = (rest & 63) << 6;

    const int l15 = lane & 15;
    const int g   = lane >> 4;
    const int l31 = lane & 31;
    const int h   = lane >> 5;

    // Q A-fragment direct from global: A[m=w*16+l15][k=g*8+j], k>=8 zero.
    bf16x8 a_q = {};
    if (g == 0)
        a_q = *(const bf16x8*)&qt[((size_t)(b * NTOK + m0 + w * 16 + l15)) * 8];

    f32x16 oacc;
    #pragma unroll
    for (int i = 0; i < 16; ++i) oacc[i] = 0.f;
    float rs0 = 0.f, rs1 = 0.f, rs2 = 0.f, rs3 = 0.f;

    const int crow = ((w >> 1) * 32 + l31) * 88;
    const int mrow = ((w & 1) * 32 + l31) * 88;

    const int itEnd = p * (64 / NSPLIT) + (64 / NSPLIT);
    for (int it = p * (64 / NSPLIT); it < itEnd; ++it) {
        const int nt0 = it << 6;
        __syncthreads();   // prev PV done reading vs/ps

        // ---- stage V tile (64 c-rows x 128B, pre-permuted cols) ----
        #pragma unroll
        for (int r = 0; r < 2; ++r) {
            const int i   = t + 256 * r;
            const int c   = i >> 3;
            const int seg = i & 7;
            *(bf16x8*)&vs[c * 88 + seg * 8] =
                *(const bf16x8*)&vbf[((size_t)(b * CCH + c)) * NTOK + nt0 + seg * 8];
        }

        // ---- K B-fragments direct from global: B[k=g*8+j][n=tn*16+l15] ----
        bf16x8 bk0 = {}, bk1 = {}, bk2 = {}, bk3 = {};
        if (g == 0) {
            const unsigned short* kb = &kt[((size_t)(b * NTOK + nt0 + l15)) * 8];
            bk0 = *(const bf16x8*)(kb);
            bk1 = *(const bf16x8*)(kb + 16 * 8);
            bk2 = *(const bf16x8*)(kb + 32 * 8);
            bk3 = *(const bf16x8*)(kb + 48 * 8);
        }

        // ---- S = Q·K^T (4 MFMAs 16x16x32; K dims >=8 are zero) ----
        const f32x4 z = {0.f, 0.f, 0.f, 0.f};
        f32x4 s0 = __builtin_amdgcn_mfma_f32_16x16x32_bf16(a_q, bk0, z, 0, 0, 0);
        f32x4 s1 = __builtin_amdgcn_mfma_f32_16x16x32_bf16(a_q, bk1, z, 0, 0, 0);
        f32x4 s2 = __builtin_amdgcn_mfma_f32_16x16x32_bf16(a_q, bk2, z, 0, 0, 0);
        f32x4 s3 = __builtin_amdgcn_mfma_f32_16x16x32_bf16(a_q, bk3, z, 0, 0, 0);

        // ---- P = exp2(S) (q carries log2e), packed b64 writes at n'=4*l15 ----
        #pragma unroll
        for (int r = 0; r < 4; ++r) {
            const float p0 = exp2f(s0[r]);
            const float p1 = exp2f(s1[r]);
            const float p2 = exp2f(s2[r]);
            const float p3 = exp2f(s3[r]);
            const unsigned int lo = __builtin_amdgcn_perm(
                __float_as_uint(p1), __float_as_uint(p0), 0x07060302u);
            const unsigned int hi = __builtin_amdgcn_perm(
                __float_as_uint(p3), __float_as_uint(p2), 0x07060302u);
            *(uint32x2*)&ps[(w * 16 + g * 4 + r) * 88 + 4 * l15] = (uint32x2){lo, hi};
            const float ssum = (p0 + p1) + (p2 + p3);
            if      (r == 0) rs0 += ssum;
            else if (r == 1) rs1 += ssum;
            else if (r == 2) rs2 += ssum;
            else             rs3 += ssum;
        }
        __syncthreads();   // vs + ps ready

        // ---- O^T += V·P^T (4 MFMAs 32x32x16) ----
        #pragma unroll
        for (int kc = 0; kc < 4; ++kc) {
            const bf16x8 a_v = *(const bf16x8*)&vs[crow + kc * 16 + h * 8];
            const bf16x8 b_p = *(const bf16x8*)&ps[mrow + kc * 16 + h * 8];
            oacc = __builtin_amdgcn_mfma_f32_32x32x16_bf16(a_v, b_p, oacc, 0, 0, 0);
        }
    }

    #pragma unroll
    for (int xm = 1; xm <= 8; xm <<= 1) {
        rs0 += __shfl_xor(rs0, xm);
        rs1 += __shfl_xor(rs1, xm);
        rs2 += __shfl_xor(rs2, xm);
        rs3 += __shfl_xor(rs3, xm);
    }
    if (l15 == 0) {
        float* lp = lpart + (size_t)(p * B + b) * NTOK + m0 + w * 16 + g * 4;
        lp[0] = rs0; lp[1] = rs1; lp[2] = rs2; lp[3] = rs3;
    }
    {
        const int mloc = (w & 1) * 32 + l31;
        #pragma unroll
        for (int reg = 0; reg < 16; ++reg) {
            const int c = (w >> 1) * 32 + (reg & 3) + 8 * (reg >> 2) + 4 * h;
            opart[((size_t)((p * B + b) * CCH + c)) * NTOK + m0 + mloc] =
                f2bf_rne(oacc[reg]);
        }
    }
}

// ---------------------------------------------------------------------------
// Kernel 3: combine NSPLIT partials + normalize + residual (pure streaming).
// ---------------------------------------------------------------------------
__global__ __launch_bounds__(256) void combine_kernel(
    const unsigned short* __restrict__ opart, const float* __restrict__ lpart,
    const float* __restrict__ x, const float* __restrict__ gamma_p,
    float* __restrict__ out, int B)
{
    const float  gm      = gamma_p[0];
    const size_t nf4     = (size_t)B * CCH * NTOK / 4;
    const size_t ostride = (size_t)B * CCH * NTOK;
    for (size_t f = (size_t)blockIdx.x * 256 + threadIdx.x; f < nf4;
         f += (size_t)gridDim.x * 256) {
        const int m4 = ((int)(f & 1023)) * 4;
        const int bc = (int)(f >> 10);
        const int bi = bc >> 6;
        const size_t obase = (size_t)bc * NTOK + m4;

        float4 osum = {0.f, 0.f, 0.f, 0.f};
        float4 lsum = {0.f, 0.f, 0.f, 0.f};
        #pragma unroll
        for (int p = 0; p < NSPLIT; ++p) {
            const ushort4 o = *(const ushort4*)&opart[obase + (size_t)p * ostride];
            const float4  l = *(const float4*)&lpart[(size_t)(p * B + bi) * NTOK + m4];
            osum.x += bf2f(o.x); osum.y += bf2f(o.y);
            osum.z += bf2f(o.z); osum.w += bf2f(o.w);
            lsum.x += l.x; lsum.y += l.y; lsum.z += l.z; lsum.w += l.w;
        }
        const float4 xv = *(const float4*)&x[obase];
        float4 r;
        r.x = osum.x * gm / lsum.x + xv.x;
        r.y = osum.y * gm / lsum.y + xv.y;
        r.z = osum.z * gm / lsum.z + xv.z;
        r.w = osum.w * gm / lsum.w + xv.w;
        *(float4*)&out[obase] = r;
    }
}

extern "C" void kernel_launch(void* const* d_in, const int* in_sizes, int n_in,
                              void* d_out, int out_size, void* d_ws, size_t ws_size,
                              hipStream_t stream) {
    const float* x     = (const float*)d_in[0];
    const float* wq    = (const float*)d_in[1];
    const float* bq    = (const float*)d_in[2];
    const float* wk    = (const float*)d_in[3];
    const float* bk    = (const float*)d_in[4];
    const float* wv    = (const float*)d_in[5];
    const float* bv    = (const float*)d_in[6];
    const float* gamma = (const float*)d_in[7];
    float* out = (float*)d_out;

    int B = in_sizes[0] / (CCH * NTOK);   // 8

    // Workspace: qt | kt (512KB each) | vbf 4MB | opart bf16 16MB | lpart 512KB
    unsigned short* wsp   = (unsigned short*)d_ws;
    unsigned short* qt    = wsp;
    unsigned short* kt    = qt + (size_t)B * NTOK * 8;
    unsigned short* vbf   = kt + (size_t)B * NTOK * 8;
    unsigned short* opart = vbf + (size_t)B * CCH * NTOK;
    float*          lpart = (float*)(opart + (size_t)NSPLIT * B * CCH * NTOK);

    proj_kernel<<<B * 64, 256, 0, stream>>>(x, wq, bq, wk, bk, wv, bv, qt, kt, vbf);
    attn_kernel<<<NSPLIT * B * 64, 256, 0, stream>>>(qt, kt, vbf, opart, lpart, B);
    combine_kernel<<<512, 256, 0, stream>>>(opart, lpart, x, gamma, out, B);
}

// Round 11
// 125.665 us; speedup vs baseline: 3.5487x; 1.0682x over previous
//
#include <hip/hip_runtime.h>
#include <math.h>

#define NTOK 4096
#define CCH  64
#define LOG2E 1.4426950408889634f
#define NSPLIT 4   // KV-split ways

typedef __attribute__((ext_vector_type(8)))  short bf16x8;   // 8 bf16 = 4 VGPRs
typedef __attribute__((ext_vector_type(4)))  float f32x4;
typedef __attribute__((ext_vector_type(16))) float f32x16;
typedef __attribute__((ext_vector_type(2)))  unsigned int uint32x2;

__device__ __forceinline__ unsigned short f2bf_rne(float f) {
    unsigned int u = __float_as_uint(f);
    u += 0x7FFFu + ((u >> 16) & 1u);
    return (unsigned short)(u >> 16);
}
__device__ __forceinline__ float bf2f(unsigned short u) {
    return __uint_as_float(((unsigned int)u) << 16);
}

// ---------------------------------------------------------------------------
// Kernel 1: MFMA projections (round-5 proven, unchanged). One GEMM per
// (b, 64-token tile): D[80x64] = [wv ; wq*log2e ; wk] * x_tile.
// Outputs qt/kt[b][n][8] (q pre-scaled by log2e) and
// vbf[b][c][tile*64 + sigma(nu)], sigma(nu) = 4*(nu&15) + (nu>>4).
// ---------------------------------------------------------------------------
__global__ __launch_bounds__(256) void proj_kernel(
    const float* __restrict__ x,
    const float* __restrict__ wq, const float* __restrict__ bq,
    const float* __restrict__ wk, const float* __restrict__ bk,
    const float* __restrict__ wv, const float* __restrict__ bv,
    unsigned short* __restrict__ qt, unsigned short* __restrict__ kt,
    unsigned short* __restrict__ vbf)
{
    __shared__ unsigned short xsb[64 * 68];  // [n][c] bf16 (B^T storage)
    __shared__ unsigned short wa[80 * 68];   // [m][c] bf16 (A storage)
    __shared__ unsigned short vtmp[64 * 66]; // [c][sigma(n)]
    __shared__ float bb[80];

    const int t  = threadIdx.x;
    const int b  = blockIdx.x >> 6;
    const int n0 = (blockIdx.x & 63) << 6;

    const int lane = t & 63;
    const int w    = t >> 6;
    const int l15  = lane & 15;
    const int g    = lane >> 4;

    {
        const int n  = t & 63;
        const int c0 = t >> 6;
        #pragma unroll
        for (int r = 0; r < 16; ++r) {
            const int c = c0 + 4 * r;
            xsb[n * 68 + c] = f2bf_rne(x[((size_t)(b * CCH + c)) * NTOK + n0 + n]);
        }
    }
    #pragma unroll
    for (int r = 0; r < 16; ++r) {
        const int i = t + 256 * r;
        wa[(i >> 6) * 68 + (i & 63)] = f2bf_rne(wv[i]);
    }
    {
        const int i0 = t, i1 = t + 256;
        wa[(64 + (i0 >> 6)) * 68 + (i0 & 63)] = f2bf_rne(wq[i0] * LOG2E);
        wa[(64 + (i1 >> 6)) * 68 + (i1 & 63)] = f2bf_rne(wq[i1] * LOG2E);
        wa[(72 + (i0 >> 6)) * 68 + (i0 & 63)] = f2bf_rne(wk[i0]);
        wa[(72 + (i1 >> 6)) * 68 + (i1 & 63)] = f2bf_rne(wk[i1]);
    }
    if (t < 80) {
        float bias;
        if (t < 64)      bias = bv[t];
        else if (t < 72) bias = bq[t - 64] * LOG2E;
        else             bias = bk[t - 72];
        bb[t] = bias;
    }
    __syncthreads();

    f32x4 acc[5];
    #pragma unroll
    for (int mt = 0; mt < 5; ++mt) acc[mt] = (f32x4){0.f, 0.f, 0.f, 0.f};
    #pragma unroll
    for (int kc = 0; kc < 2; ++kc) {
        const bf16x8 bx = *(const bf16x8*)&xsb[(w * 16 + l15) * 68 + kc * 32 + g * 8];
        #pragma unroll
        for (int mt = 0; mt < 5; ++mt) {
            const bf16x8 aw = *(const bf16x8*)&wa[(mt * 16 + l15) * 68 + kc * 32 + g * 8];
            acc[mt] = __builtin_amdgcn_mfma_f32_16x16x32_bf16(aw, bx, acc[mt], 0, 0, 0);
        }
    }

    const int n = w * 16 + l15;
    #pragma unroll
    for (int mt = 0; mt < 4; ++mt) {
        #pragma unroll
        for (int r = 0; r < 4; ++r) {
            const int c = mt * 16 + g * 4 + r;
            vtmp[c * 66 + 4 * l15 + w] = f2bf_rne(acc[mt][r] + bb[c]);
        }
    }
    {
        unsigned short vals[4];
        #pragma unroll
        for (int r = 0; r < 4; ++r)
            vals[r] = f2bf_rne(acc[4][r] + bb[64 + g * 4 + r]);
        const unsigned int lo = (unsigned int)vals[0] | ((unsigned int)vals[1] << 16);
        const unsigned int hi = (unsigned int)vals[2] | ((unsigned int)vals[3] << 16);
        unsigned short* dst = ((g < 2) ? qt : kt) +
                              ((size_t)(b * NTOK + n0 + n)) * 8 + (g & 1) * 4;
        *(uint32x2*)dst = (uint32x2){lo, hi};
    }
    __syncthreads();

    {
        const int c = t >> 2;
        const int q = t & 3;
        unsigned short* dst = vbf + ((size_t)(b * CCH + c)) * NTOK + n0 + q * 16;
        *(bf16x8*)dst       = *(const bf16x8*)&vtmp[c * 66 + q * 16];
        *(bf16x8*)(dst + 8) = *(const bf16x8*)&vtmp[c * 66 + q * 16 + 8];
    }
}

// ---------------------------------------------------------------------------
// Kernel 2: MFMA flash attention, KV-split 4 ways. CHANGES vs round 10:
//  (a) raw-HW exp: __builtin_amdgcn_exp2f (single v_exp_f32; libm exp2f's
//      range-check wrapper was bloating the 63%-busy VALU pipe),
//  (b) register software-pipeline: V-tile + K-frags for iter it+1 prefetched
//      into VGPRs while iter it computes; top-of-iter ds_write consumes LAST
//      iter's regs -> global latency covered by a full iteration,
//  (c) running source pointers (+64 tokens/iter) replace re-derived addresses.
// ---------------------------------------------------------------------------
__global__ __launch_bounds__(256, 6) void attn_kernel(
    const unsigned short* __restrict__ qt, const unsigned short* __restrict__ kt,
    const unsigned short* __restrict__ vbf,
    unsigned short* __restrict__ opart, float* __restrict__ lpart, int B)
{
    __shared__ unsigned short vs[64 * 88];  // [c][n'] pre-permuted
    __shared__ unsigned short ps[64 * 88];  // [m][n'] bf16 P

    const int t    = threadIdx.x;
    const int lane = t & 63;
    const int w    = t >> 6;
    const int p    = blockIdx.x / (B * 64);
    const int rest = blockIdx.x % (B * 64);
    const int b    = rest >> 6;
    const int m0   = (rest & 63) << 6;

    const int l15 = lane & 15;
    const int g   = lane >> 4;
    const int l31 = lane & 31;
    const int h   = lane >> 5;

    const int NIT     = 64 / NSPLIT;        // 16 KV tiles per block
    const int itStart = p * NIT;

    // ---- Q A-fragment direct from global (k>=8 rows zero) ----
    bf16x8 a_q = {};
    if (g == 0)
        a_q = *(const bf16x8*)&qt[((size_t)(b * NTOK + m0 + w * 16 + l15)) * 8];

    // ---- per-thread V staging pointers (two 16B chunks per thread) ----
    const int c0  = t >> 3, seg = t & 7;
    const int c1  = c0 + 32;
    const unsigned short* vsrc0 = vbf + ((size_t)(b * CCH + c0)) * NTOK
                                      + itStart * 64 + seg * 8;
    const unsigned short* vsrc1 = vbf + ((size_t)(b * CCH + c1)) * NTOK
                                      + itStart * 64 + seg * 8;
    unsigned short* vdst0 = &vs[c0 * 88 + seg * 8];
    unsigned short* vdst1 = &vs[c1 * 88 + seg * 8];

    // ---- K fragment source (only g==0 lanes load; others stay zero) ----
    const unsigned short* ksrc = kt + ((size_t)(b * NTOK + itStart * 64 + l15)) * 8;

    // ---- prefetch iteration 0 ----
    bf16x8 vreg0 = *(const bf16x8*)vsrc0;
    bf16x8 vreg1 = *(const bf16x8*)vsrc1;
    bf16x8 kr0 = {}, kr1 = {}, kr2 = {}, kr3 = {};
    if (g == 0) {
        kr0 = *(const bf16x8*)(ksrc);
        kr1 = *(const bf16x8*)(ksrc + 128);   // +16 tokens * 8
        kr2 = *(const bf16x8*)(ksrc + 256);
        kr3 = *(const bf16x8*)(ksrc + 384);
    }

    f32x16 oacc;
    #pragma unroll
    for (int i = 0; i < 16; ++i) oacc[i] = 0.f;
    float rs0 = 0.f, rs1 = 0.f, rs2 = 0.f, rs3 = 0.f;

    const int crow = ((w >> 1) * 32 + l31) * 88;
    const int mrow = ((w & 1) * 32 + l31) * 88;

    for (int it = 0; it < NIT; ++it) {
        __syncthreads();   // prev PV done reading vs/ps

        // ---- commit prefetched V tile to LDS (no vmcnt stall: loaded 1 iter ago)
        *(bf16x8*)vdst0 = vreg0;
        *(bf16x8*)vdst1 = vreg1;

        // ---- S = Q·K^T with current K regs ----
        const f32x4 z = {0.f, 0.f, 0.f, 0.f};
        f32x4 s0 = __builtin_amdgcn_mfma_f32_16x16x32_bf16(a_q, kr0, z, 0, 0, 0);
        f32x4 s1 = __builtin_amdgcn_mfma_f32_16x16x32_bf16(a_q, kr1, z, 0, 0, 0);
        f32x4 s2 = __builtin_amdgcn_mfma_f32_16x16x32_bf16(a_q, kr2, z, 0, 0, 0);
        f32x4 s3 = __builtin_amdgcn_mfma_f32_16x16x32_bf16(a_q, kr3, z, 0, 0, 0);

        // ---- prefetch next iteration's V + K into registers ----
        if (it + 1 < NIT) {
            vsrc0 += 64;  vsrc1 += 64;  ksrc += 64 * 8;
            vreg0 = *(const bf16x8*)vsrc0;
            vreg1 = *(const bf16x8*)vsrc1;
            if (g == 0) {
                kr0 = *(const bf16x8*)(ksrc);
                kr1 = *(const bf16x8*)(ksrc + 128);
                kr2 = *(const bf16x8*)(ksrc + 256);
                kr3 = *(const bf16x8*)(ksrc + 384);
            }
        }

        // ---- P = exp2(S) (q carries log2e), raw v_exp_f32 ----
        #pragma unroll
        for (int r = 0; r < 4; ++r) {
            const float p0 = __builtin_amdgcn_exp2f(s0[r]);
            const float p1 = __builtin_amdgcn_exp2f(s1[r]);
            const float p2 = __builtin_amdgcn_exp2f(s2[r]);
            const float p3 = __builtin_amdgcn_exp2f(s3[r]);
            const unsigned int lo = __builtin_amdgcn_perm(
                __float_as_uint(p1), __float_as_uint(p0), 0x07060302u);
            const unsigned int hi = __builtin_amdgcn_perm(
                __float_as_uint(p3), __float_as_uint(p2), 0x07060302u);
            *(uint32x2*)&ps[(w * 16 + g * 4 + r) * 88 + 4 * l15] = (uint32x2){lo, hi};
            const float ssum = (p0 + p1) + (p2 + p3);
            if      (r == 0) rs0 += ssum;
            else if (r == 1) rs1 += ssum;
            else if (r == 2) rs2 += ssum;
            else             rs3 += ssum;
        }
        __syncthreads();   // vs + ps ready

        // ---- O^T += V·P^T (4 MFMAs 32x32x16) ----
        #pragma unroll
        for (int kc = 0; kc < 4; ++kc) {
            const bf16x8 a_v = *(const bf16x8*)&vs[crow + kc * 16 + h * 8];
            const bf16x8 b_p = *(const bf16x8*)&ps[mrow + kc * 16 + h * 8];
            oacc = __builtin_amdgcn_mfma_f32_32x32x16_bf16(a_v, b_p, oacc, 0, 0, 0);
        }
    }

    #pragma unroll
    for (int xm = 1; xm <= 8; xm <<= 1) {
        rs0 += __shfl_xor(rs0, xm);
        rs1 += __shfl_xor(rs1, xm);
        rs2 += __shfl_xor(rs2, xm);
        rs3 += __shfl_xor(rs3, xm);
    }
    if (l15 == 0) {
        float* lp = lpart + (size_t)(p * B + b) * NTOK + m0 + w * 16 + g * 4;
        lp[0] = rs0; lp[1] = rs1; lp[2] = rs2; lp[3] = rs3;
    }
    {
        const int mloc = (w & 1) * 32 + l31;
        #pragma unroll
        for (int reg = 0; reg < 16; ++reg) {
            const int c = (w >> 1) * 32 + (reg & 3) + 8 * (reg >> 2) + 4 * h;
            opart[((size_t)((p * B + b) * CCH + c)) * NTOK + m0 + mloc] =
                f2bf_rne(oacc[reg]);
        }
    }
}

// ---------------------------------------------------------------------------
// Kernel 3: combine NSPLIT partials + normalize + residual (pure streaming).
// ---------------------------------------------------------------------------
__global__ __launch_bounds__(256) void combine_kernel(
    const unsigned short* __restrict__ opart, const float* __restrict__ lpart,
    const float* __restrict__ x, const float* __restrict__ gamma_p,
    float* __restrict__ out, int B)
{
    const float  gm      = gamma_p[0];
    const size_t nf4     = (size_t)B * CCH * NTOK / 4;
    const size_t ostride = (size_t)B * CCH * NTOK;
    for (size_t f = (size_t)blockIdx.x * 256 + threadIdx.x; f < nf4;
         f += (size_t)gridDim.x * 256) {
        const int m4 = ((int)(f & 1023)) * 4;
        const int bc = (int)(f >> 10);
        const int bi = bc >> 6;
        const size_t obase = (size_t)bc * NTOK + m4;

        float4 osum = {0.f, 0.f, 0.f, 0.f};
        float4 lsum = {0.f, 0.f, 0.f, 0.f};
        #pragma unroll
        for (int p = 0; p < NSPLIT; ++p) {
            const ushort4 o = *(const ushort4*)&opart[obase + (size_t)p * ostride];
            const float4  l = *(const float4*)&lpart[(size_t)(p * B + bi) * NTOK + m4];
            osum.x += bf2f(o.x); osum.y += bf2f(o.y);
            osum.z += bf2f(o.z); osum.w += bf2f(o.w);
            lsum.x += l.x; lsum.y += l.y; lsum.z += l.z; lsum.w += l.w;
        }
        const float4 xv = *(const float4*)&x[obase];
        float4 r;
        r.x = osum.x * gm / lsum.x + xv.x;
        r.y = osum.y * gm / lsum.y + xv.y;
        r.z = osum.z * gm / lsum.z + xv.z;
        r.w = osum.w * gm / lsum.w + xv.w;
        *(float4*)&out[obase] = r;
    }
}

extern "C" void kernel_launch(void* const* d_in, const int* in_sizes, int n_in,
                              void* d_out, int out_size, void* d_ws, size_t ws_size,
                              hipStream_t stream) {
    const float* x     = (const float*)d_in[0];
    const float* wq    = (const float*)d_in[1];
    const float* bq    = (const float*)d_in[2];
    const float* wk    = (const float*)d_in[3];
    const float* bk    = (const float*)d_in[4];
    const float* wv    = (const float*)d_in[5];
    const float* bv    = (const float*)d_in[6];
    const float* gamma = (const float*)d_in[7];
    float* out = (float*)d_out;

    int B = in_sizes[0] / (CCH * NTOK);   // 8

    // Workspace: qt | kt (512KB each) | vbf 4MB | opart bf16 16MB | lpart 512KB
    unsigned short* wsp   = (unsigned short*)d_ws;
    unsigned short* qt    = wsp;
    unsigned short* kt    = qt + (size_t)B * NTOK * 8;
    unsigned short* vbf   = kt + (size_t)B * NTOK * 8;
    unsigned short* opart = vbf + (size_t)B * CCH * NTOK;
    float*          lpart = (float*)(opart + (size_t)NSPLIT * B * CCH * NTOK);

    proj_kernel<<<B * 64, 256, 0, stream>>>(x, wq, bq, wk, bk, wv, bv, qt, kt, vbf);
    attn_kernel<<<NSPLIT * B * 64, 256, 0, stream>>>(qt, kt, vbf, opart, lpart, B);
    combine_kernel<<<512, 256, 0, stream>>>(opart, lpart, x, gamma, out, B);
}